// Round 14
// baseline (83.829 us; speedup 1.0000x reference)
//
#include <hip/hip_runtime.h>
#include <hip/hip_fp16.h>

// ContinuousFilterConv on MI355X (gfx950), round 14.
// filtered[e,i] = sum_{u,j} h[e,u] * tm[e,j] * W2ext[u, i*128+j]
// k2 outer-product GEMM + k1m MFMA edge-prep unchanged (round 13).
// Round 14: W2->w2c conversion regridded 129 -> 516 blocks (one K-step per
// block; was the prep long-pole at 0.5 blocks/CU) and made register-only
// (each thread's 16 coalesced f32 = exactly 2 output frags). Wt/W1 conversion
// and d_out zeroing folded into the same kprep launch (k0all eliminated).

typedef _Float16 f16;
typedef __attribute__((ext_vector_type(8))) f16 f16x8;
typedef __attribute__((ext_vector_type(4))) float f32x4;
typedef __attribute__((ext_vector_type(4))) unsigned int u32x4;

#define NEDGE 8192
#define NNODE 20000
#define NG    50
#define KSTEPS 516                        // 129 u-rows * 128 j / 32
#define W2C_BYTES (KSTEPS * 8192)         // [step][nt8][lane64][8] f16
#define HT_BYTES (64 * 132 * 128 * 2)     // [eb][u(132, 128=ones)][el(128)] f16
#define TM_BYTES (NEDGE * 128 * 2)        // [e][j^swz] f16 (mask folded, pre-swizzled)
#define WTC_BYTES (4 * 8 * 64 * 8 * 2)    // Wt frag-linear f16, 32 KB
#define W1C_BYTES (2 * 8 * 64 * 8 * 2)    // W1ext frag-linear f16 (64 K rows), 16 KB
#define FP_BYTES ((size_t)8 * NEDGE * 128 * 4)  // f32 partials [c][e][i] = 32 MB

// k2 LDS map (bytes)
#define LDS_H   0                         // 20 rows x 256 B = 5120
#define LDS_TM  5120                      // 128 x 256 B (swizzled) = 32768
#define LDS_TOT 37888

// k1m LDS map (bytes)
#define K1_SRC 0                          // [64e][128u] f16 swz = 16384
#define K1_DF  16384                      // [64e][64g]  f16 swz = 8192
#define K1_MSK 24576                      // mask f32 [64] = 256
#define K1_TOT 24832

static __device__ __forceinline__ float fsilu(float x) { return x / (1.0f + __expf(-x)); }

static __device__ __forceinline__ void gll16(const void* g, void* l) {
  __builtin_amdgcn_global_load_lds(
      (const __attribute__((address_space(1))) unsigned int*)g,
      (__attribute__((address_space(3))) unsigned int*)l, 16, 0, 0);
}

// ---- kprep: {W2->w2c (516 blks) | Wt->wtc (4) | W1->w1c (1) | zero out} ----
// blocks [0,516): (u = b>>2, s = b&3) one K-step of one W2ext row, reg-only
// blocks [516,520): Wt -> wtc ; block 520: W1ext -> w1c
// blocks [521, 1146): zero d_out
__global__ __launch_bounds__(256) void kprep(const float* __restrict__ W2,
                                             const float* __restrict__ b2,
                                             const float* __restrict__ W1,
                                             const float* __restrict__ B1,
                                             const float* __restrict__ WT,
                                             f16* __restrict__ w2c,
                                             f16* __restrict__ wtc,
                                             f16* __restrict__ w1c,
                                             float* __restrict__ out, int nz4) {
  const int bid = blockIdx.x, tid = threadIdx.x;

  if (bid < 516) {
    // ---- one K-step (32 j) of one W2ext row -> 2 frags per thread ----
    const int u = bid >> 2, s = bid & 3;
    const int i = tid >> 1, half = tid & 1;
    const float* src = ((u < 128) ? (W2 + (size_t)u * 16384) : b2)
                       + i * 128 + s * 32 + half * 16;
    union { f16 s16[16]; u32x4 v[2]; } pk;
#pragma unroll
    for (int q = 0; q < 4; ++q) {
      f32x4 v = *(const f32x4*)(src + q * 4);
#pragma unroll
      for (int r = 0; r < 4; ++r) pk.s16[q * 4 + r] = (f16)v[r];
    }
    const int nt = i >> 4, l15 = i & 15;
    u32x4* dst = (u32x4*)w2c + (size_t)(u * 4 + s) * 512 + nt * 64 + l15;
    dst[(half * 2 + 0) * 16] = pk.v[0];
    dst[(half * 2 + 1) * 16] = pk.v[1];
    return;
  }
  if (bid < 520) {
    // ---- Wt -> wtc frags for K-step (bid-516) ----
    int step = bid - 516;
#pragma unroll
    for (int q = 0; q < 2; ++q) {
      int fi = q * 256 + tid;                              // 512 frags/step
      int lane = fi & 63, nt = fi >> 6;
      int j = nt * 16 + (lane & 15);
      union { f16 s[8]; u32x4 v; } pk;
#pragma unroll
      for (int r = 0; r < 8; ++r) {
        int u = step * 32 + (lane >> 4) * 8 + r;
        pk.s[r] = (f16)WT[u * 128 + j];
      }
      *((u32x4*)wtc + (step * 8 + nt) * 64 + lane) = pk.v;
    }
    return;
  }
  if (bid == 520) {
    // ---- W1ext -> w1c: rows 0..49 = W1, 50..62 = 0, 63 = b1 ----
#pragma unroll
    for (int q = 0; q < 4; ++q) {
      int fi = q * 256 + tid;                              // 1024 frags
      int lane = fi & 63, nt = (fi >> 6) & 7, step = fi >> 9;
      int j = nt * 16 + (lane & 15);
      union { f16 s[8]; u32x4 v; } pk;
#pragma unroll
      for (int r = 0; r < 8; ++r) {
        int g = step * 32 + (lane >> 4) * 8 + r;
        float v = (g < 50) ? W1[g * 128 + j] : ((g == 63) ? B1[j] : 0.0f);
        pk.s[r] = (f16)v;
      }
      *((u32x4*)w1c + (step * 8 + nt) * 64 + lane) = pk.v;
    }
    return;
  }
  // ---- zero d_out ----
  {
    int base = (bid - 521) * 1024;
    f32x4 z = {0.f, 0.f, 0.f, 0.f};
#pragma unroll
    for (int k = 0; k < 4; ++k) {
      int i4 = base + k * 256 + tid;
      if (i4 < nz4) ((f32x4*)out)[i4] = z;
    }
  }
}

// ---- k1m: MFMA edge prep. 128 blocks x 64 edges, 4 waves of 16e x 128n ----
// t = srcF16 @ wtc  -> tm = mask * t  (tmo, pre-swizzled [e][j^swz])
// h = silu(dfF16 @ w1c)               (ht2 [eb][u][el], + ones row 128)
__global__ __launch_bounds__(256) void k1m(const float* __restrict__ NF,
                                           const int*   __restrict__ EI,
                                           const float* __restrict__ DI,
                                           const f16* __restrict__ wtc,
                                           const f16* __restrict__ w1c,
                                           f16* __restrict__ ht2,
                                           f16* __restrict__ tmo) {
  __shared__ u32x4 smem_v[K1_TOT / 16];
  char* smem = (char*)smem_v;
  const int bid = blockIdx.x, tid = threadIdx.x;
  const int e0g = bid * 64;                 // global first edge
  const int eb  = bid >> 1;                 // 128-edge block for ht2
  const int el0 = (bid & 1) * 64;           // offset inside ht2 e-dim

  if (tid < 64) {
    float d = DI[e0g + tid];
    *(float*)(smem + K1_MSK + tid * 4) = (d <= 8.0f) ? 1.0f : 0.0f;
  }
  {
    int e = tid >> 2, g0 = (tid & 3) * 16;
    float d = DI[e0g + e];
    union { f16 s[16]; u32x4 v[2]; } pk;
#pragma unroll
    for (int gg = 0; gg < 16; ++gg) {
      int g = g0 + gg;
      float x = d - (float)g * (30.0f / 49.0f);
      float v = (g < 50) ? __expf(-10.0f * x * x) : ((g == 63) ? 1.0f : 0.0f);
      pk.s[gg] = (f16)v;
    }
    int base = e * 128 + g0 * 2, sw = (e & 7) << 4;
    *(u32x4*)(smem + K1_DF + ((base) ^ sw))      = pk.v[0];
    *(u32x4*)(smem + K1_DF + ((base + 16) ^ sw)) = pk.v[1];
  }
#pragma unroll
  for (int p = 0; p < 8; ++p) {
    int e = p * 8 + (tid >> 5);
    int u0 = (tid & 31) * 4;
    int row = EI[e0g + e];
    f32x4 v = *(const f32x4*)(NF + (size_t)row * 128 + u0);
    union { f16 s[4]; unsigned long long q; } pk;
#pragma unroll
    for (int r = 0; r < 4; ++r) pk.s[r] = (f16)v[r];
    int addr = e * 256 + u0 * 2;
    *(unsigned long long*)(smem + K1_SRC + (addr ^ ((e & 7) << 4))) = pk.q;
  }
  __syncthreads();

  const int w = tid >> 6, lane = tid & 63;
  const int l15 = lane & 15, g4 = lane >> 4;
  const int erow = w * 16;
  const int asw = (l15 & 7) << 4;

  f32x4 at[8], ah[8];
#pragma unroll
  for (int nt = 0; nt < 8; ++nt) {
    at[nt] = (f32x4){0.f, 0.f, 0.f, 0.f};
    ah[nt] = (f32x4){0.f, 0.f, 0.f, 0.f};
  }
  const f16x8* wtp = (const f16x8*)wtc;
  const f16x8* w1p = (const f16x8*)w1c;

#pragma unroll
  for (int step = 0; step < 4; ++step) {
    int aaddr = (erow + l15) * 256 + step * 64 + g4 * 16;
    f16x8 a = *(const f16x8*)(smem + K1_SRC + (aaddr ^ asw));
#pragma unroll
    for (int nt = 0; nt < 8; ++nt)
      at[nt] = __builtin_amdgcn_mfma_f32_16x16x32_f16(a, wtp[(step * 8 + nt) * 64 + lane], at[nt], 0, 0, 0);
  }
#pragma unroll
  for (int step = 0; step < 2; ++step) {
    int aaddr = (erow + l15) * 128 + step * 64 + g4 * 16;
    f16x8 a = *(const f16x8*)(smem + K1_DF + (aaddr ^ asw));
#pragma unroll
    for (int nt = 0; nt < 8; ++nt)
      ah[nt] = __builtin_amdgcn_mfma_f32_16x16x32_f16(a, w1p[(step * 8 + nt) * 64 + lane], ah[nt], 0, 0, 0);
  }

  const float* mk = (const float*)(smem + K1_MSK);
#pragma unroll
  for (int r = 0; r < 4; ++r) {
    int el_ = erow + g4 * 4 + r;
    float m = mk[el_];
    int sw2 = (el_ & 7) << 4;
    char* rowp = (char*)tmo + (size_t)(e0g + el_) * 256;
#pragma unroll
    for (int nt = 0; nt < 8; ++nt)
      *(f16*)(rowp + (((nt * 16 + l15) * 2) ^ sw2)) = (f16)(m * at[nt][r]);
  }
#pragma unroll
  for (int r = 0; r < 4; ++r) {
    int el_ = el0 + erow + g4 * 4 + r;
#pragma unroll
    for (int nt = 0; nt < 8; ++nt) {
      int u = nt * 16 + l15;
      ht2[((size_t)eb * 132 + u) * 128 + el_] = (f16)fsilu(ah[nt][r]);
    }
  }
  if (tid < 64) ht2[((size_t)eb * 132 + 128) * 128 + el0 + tid] = (f16)1.0f;
}

// ---------------- k2: fused outer-product GEMM + partial store --------------
template<int MODE>
__global__ __launch_bounds__(256, 2) void k2_gemm(const f16* __restrict__ w2c,
                                                  const f16* __restrict__ ht2,
                                                  const f16* __restrict__ tm,
                                                  const int* __restrict__ EI,
                                                  float* __restrict__ fpart,
                                                  float* __restrict__ msg) {
  __shared__ u32x4 smem_v[LDS_TOT / 16];
  char* smem = (char*)smem_v;

  const int bid = blockIdx.x;
  const int c   = bid & 7;
  const int eb  = bid >> 3;
  const int e0  = eb * 128;
  const int nu  = (c == 7) ? 17 : 16;
  const int tid = threadIdx.x, w = tid >> 6, lane = tid & 63;
  const int l15 = lane & 15, g4 = lane >> 4;
  const int wm = w >> 1, wn = w & 1;

  // ---- B phases 0/1 issued FIRST: latency overlaps staging + barrier ----
  const char* bp = (const char*)w2c + (size_t)(c * 64) * 8192 + wn * 4096 + lane * 16;
  f16x8 B0[4], B1[4];
#pragma unroll
  for (int nt = 0; nt < 4; ++nt) B0[nt] = *(const f16x8*)(bp + nt * 1024);
#pragma unroll
  for (int nt = 0; nt < 4; ++nt) B1[nt] = *(const f16x8*)(bp + 8192 + nt * 1024);

  {
    const char* tsrc = (const char*)tm + (size_t)e0 * 256 + w * 8192;
#pragma unroll
    for (int q = 0; q < 8; ++q)
      gll16(tsrc + q * 1024 + lane * 16,
            smem + LDS_TM + w * 8192 + q * 1024 + lane * 16);
  }
  if (w == 0) {   // 20 h rows
    const char* hsrc = (const char*)ht2 + ((size_t)eb * 132 + c * 16) * 256;
#pragma unroll
    for (int q = 0; q < 5; ++q)
      gll16(hsrc + q * 1024 + lane * 16, smem + LDS_H + q * 1024 + lane * 16);
  }
  __syncthreads();

  f16x8 Tall[4][4];
  {
    const int tmrow = LDS_TM + (wm * 64 + l15) * 256;
    const int colsw = (l15 & 7) << 4;
#pragma unroll
    for (int rt = 0; rt < 4; ++rt)
#pragma unroll
      for (int jc = 0; jc < 4; ++jc)
        Tall[rt][jc] = *(const f16x8*)(smem + tmrow + rt * 4096 +
                                       ((jc * 64 + g4 * 16) ^ colsw));
  }
  const __half* hbase = (const __half*)(smem + LDS_H) + wm * 64 + l15;

  __half2 hc[4], hn[4];
#pragma unroll
  for (int rt = 0; rt < 4; ++rt) hc[rt] = __half2half2(hbase[rt * 16]);

  size_t off = 2 * 8192;
  f32x4 acc[4][4];
#pragma unroll
  for (int rt = 0; rt < 4; ++rt)
#pragma unroll
    for (int nt = 0; nt < 4; ++nt) acc[rt][nt] = (f32x4){0.f, 0.f, 0.f, 0.f};

  for (int u = 0; u < nu; ++u) {
#pragma unroll
    for (int jc = 0; jc < 4; ++jc) {
      if (jc == 1) {
#pragma unroll
        for (int rt = 0; rt < 4; ++rt)
          hn[rt] = __half2half2(hbase[(u + 1) * 128 + rt * 16]);
      }
      union uf { f16x8 v; __half2 h[4]; };
      uf a[4];
#pragma unroll
      for (int rt = 0; rt < 4; ++rt) {
        uf t; t.v = Tall[rt][jc];
#pragma unroll
        for (int q = 0; q < 4; ++q) a[rt].h[q] = __hmul2(t.h[q], hc[rt]);
      }
      __builtin_amdgcn_s_setprio(1);
#pragma unroll
      for (int nt = 0; nt < 4; ++nt) {
        if ((jc & 1) == 0) {
#pragma unroll
          for (int rt = 0; rt < 4; ++rt)
            acc[rt][nt] = __builtin_amdgcn_mfma_f32_16x16x32_f16(a[rt].v, B0[nt], acc[rt][nt], 0, 0, 0);
          B0[nt] = *(const f16x8*)(bp + off + nt * 1024);
        } else {
#pragma unroll
          for (int rt = 0; rt < 4; ++rt)
            acc[rt][nt] = __builtin_amdgcn_mfma_f32_16x16x32_f16(a[rt].v, B1[nt], acc[rt][nt], 0, 0, 0);
          B1[nt] = *(const f16x8*)(bp + off + nt * 1024);
        }
      }
      __builtin_amdgcn_s_setprio(0);
      off += 8192;
    }
#pragma unroll
    for (int rt = 0; rt < 4; ++rt) hc[rt] = hn[rt];
  }

  if (MODE == 0) {
#pragma unroll
    for (int rt = 0; rt < 4; ++rt) {
#pragma unroll
      for (int r = 0; r < 4; ++r) {
        int e = e0 + wm * 64 + rt * 16 + g4 * 4 + r;
        float* prow = fpart + ((size_t)c * NEDGE + e) * 128 + wn * 64 + l15;
#pragma unroll
        for (int nt = 0; nt < 4; ++nt)
          prow[nt * 16] = acc[rt][nt][r];
      }
    }
  } else {
    const int* dst = EI + NEDGE;
#pragma unroll
    for (int rt = 0; rt < 4; ++rt) {
#pragma unroll
      for (int r = 0; r < 4; ++r) {
        int e = e0 + wm * 64 + rt * 16 + g4 * 4 + r;
        float* row = msg + (size_t)dst[e] * 128 + wn * 64 + l15;
#pragma unroll
        for (int nt = 0; nt < 4; ++nt)
          atomicAdd(row + nt * 16, acc[rt][nt][r]);
      }
    }
  }
}

// -------- k4: sum 8 chunk-partials per edge, scatter-add to nodes -----------
__global__ __launch_bounds__(256) void k4_reduce(const float* __restrict__ fp,
                                                 const int* __restrict__ EI,
                                                 float* __restrict__ out) {
  int gid = blockIdx.x * 256 + threadIdx.x;     // 262144 = 8192 e * 32
  int e  = gid >> 5;
  int i0 = (gid & 31) << 2;
  f32x4 s = {0.f, 0.f, 0.f, 0.f};
#pragma unroll
  for (int cc = 0; cc < 8; ++cc) {
    f32x4 v = *(const f32x4*)(fp + ((size_t)cc * NEDGE + e) * 128 + i0);
    s[0] += v[0]; s[1] += v[1]; s[2] += v[2]; s[3] += v[3];
  }
  float* row = out + (size_t)EI[NEDGE + e] * 128 + i0;
  atomicAdd(row + 0, s[0]);
  atomicAdd(row + 1, s[1]);
  atomicAdd(row + 2, s[2]);
  atomicAdd(row + 3, s[3]);
}

// ---------------- k3: out = silu(out) ----------------------------------------
__global__ __launch_bounds__(256) void k3_silu(float* __restrict__ out, int n4) {
  int idx = blockIdx.x * 256 + threadIdx.x;
  int stride = gridDim.x * 256;
  f32x4* p = (f32x4*)out;
  for (; idx < n4; idx += stride) {
    f32x4 v = p[idx];
#pragma unroll
    for (int cc = 0; cc < 4; ++cc) v[cc] = fsilu(v[cc]);
    p[idx] = v;
  }
}

extern "C" void kernel_launch(void* const* d_in, const int* in_sizes, int n_in,
                              void* d_out, int out_size, void* d_ws, size_t ws_size,
                              hipStream_t stream) {
  const float* NF = (const float*)d_in[0];
  const int*   EI = (const int*)  d_in[1];
  const float* DI = (const float*)d_in[2];
  const float* W1 = (const float*)d_in[3];
  const float* B1 = (const float*)d_in[4];
  const float* W2 = (const float*)d_in[5];
  const float* B2 = (const float*)d_in[6];
  const float* WT = (const float*)d_in[7];
  float* out = (float*)d_out;

  char* base = (char*)d_ws;
  f16*   w2c = (f16*)base;
  f16*   ht2 = (f16*)(base + W2C_BYTES);
  f16*   tmo = (f16*)(base + W2C_BYTES + HT_BYTES);
  f16*   wtc = (f16*)(base + W2C_BYTES + HT_BYTES + TM_BYTES);
  f16*   w1c = (f16*)(base + W2C_BYTES + HT_BYTES + TM_BYTES + WTC_BYTES);
  float* fp  = (float*)(base + W2C_BYTES + HT_BYTES + TM_BYTES + WTC_BYTES + W1C_BYTES);
  size_t need_min  = (size_t)W2C_BYTES + HT_BYTES + TM_BYTES + WTC_BYTES + W1C_BYTES;
  size_t need_fast = need_min + FP_BYTES;
  if (ws_size < need_min) return;  // insufficient scratch: fail loudly
  const bool fast = (ws_size >= need_fast);

  int nz4 = out_size / 4;
  kprep<<<dim3(1146), dim3(256), 0, stream>>>(W2, B2, W1, B1, WT, w2c, wtc, w1c, out, nz4);
  k1m  <<<dim3(128),  dim3(256), 0, stream>>>(NF, EI, DI, wtc, w1c, ht2, tmo);
  if (fast) {
    k2_gemm<0><<<dim3(512),  dim3(256), 0, stream>>>(w2c, ht2, tmo, EI, fp, out);
    k4_reduce <<<dim3(1024), dim3(256), 0, stream>>>(fp, EI, out);
  } else {
    k2_gemm<1><<<dim3(512),  dim3(256), 0, stream>>>(w2c, ht2, tmo, EI, fp, out);
  }
  k3_silu<<<dim3(1024), dim3(256), 0, stream>>>(out, nz4);
}

// Round 15
// 82.088 us; speedup vs baseline: 1.0212x; 1.0212x over previous
//
#include <hip/hip_runtime.h>
#include <hip/hip_fp16.h>

// ContinuousFilterConv on MI355X (gfx950), round 15.
// filtered[e,i] = sum_{u,j} h[e,u] * tm[e,j] * W2ext[u, i*128+j]
// k2 outer-product GEMM loop unchanged (round-8 loop, B-first prologue).
// Round 15: (1) kprep+k1m merged into ONE launch `kpre` — edge blocks build
// their own Wt/W1 frag tables in LDS (removes the inter-kernel dependency),
// so W2-convert, edge-prep and d_out zeroing co-schedule; (2) fp partials
// relaid out as [e][c][i] so k4's 8 per-edge reads are one contiguous 4 KB.

typedef _Float16 f16;
typedef __attribute__((ext_vector_type(8))) f16 f16x8;
typedef __attribute__((ext_vector_type(4))) float f32x4;
typedef __attribute__((ext_vector_type(4))) unsigned int u32x4;

#define NEDGE 8192
#define NNODE 20000
#define NG    50
#define KSTEPS 516                        // 129 u-rows * 128 j / 32
#define W2C_BYTES (KSTEPS * 8192)         // [step][nt8][lane64][8] f16
#define HT_BYTES (64 * 132 * 128 * 2)     // [eb][u(132, 128=ones)][el(128)] f16
#define TM_BYTES (NEDGE * 128 * 2)        // [e][j^swz] f16 (mask folded, pre-swizzled)
#define FP_BYTES ((size_t)NEDGE * 8 * 128 * 4)  // f32 partials [e][c][i] = 32 MB

// k2 LDS map (bytes)
#define LDS_H   0                         // 20 rows x 256 B = 5120
#define LDS_TM  5120                      // 128 x 256 B (swizzled) = 32768
#define LDS_TOT 37888

// kpre edge-path LDS map (bytes)
#define K_SRC 0                           // [64e][128u] f16 swz = 16384
#define K_DF  16384                       // [64e][64g]  f16 swz = 8192
#define K_MSK 24576                       // mask f32 [64] = 256
#define K_WTC 24832                       // Wt frags  [s4][nt8][l64][8] = 32768
#define K_W1C 57600                       // W1 frags  [s2][nt8][l64][8] = 16384
#define K_TOT 73984

static __device__ __forceinline__ float fsilu(float x) { return x / (1.0f + __expf(-x)); }

static __device__ __forceinline__ void gll16(const void* g, void* l) {
  __builtin_amdgcn_global_load_lds(
      (const __attribute__((address_space(1))) unsigned int*)g,
      (__attribute__((address_space(3))) unsigned int*)l, 16, 0, 0);
}

// ---- kpre: {W2->w2c (516) | MFMA edge-prep (128, self-converting) | zero} --
// blocks [0,516): (u = b>>2, s = b&3) one K-step of one W2ext row, reg-only
// blocks [516,644): edge blocks — convert Wt/W1ext to LDS frags, then
//   t = srcF16 @ Wt -> tmo (mask folded, pre-swizzled), h = silu(df@W1ext)
//   -> ht2 (+ ones row), b1 folded via df channel 63.
// blocks [644,1269): zero d_out
__global__ __launch_bounds__(256) void kpre(const float* __restrict__ W2,
                                            const float* __restrict__ b2,
                                            const float* __restrict__ W1,
                                            const float* __restrict__ B1,
                                            const float* __restrict__ WT,
                                            const float* __restrict__ NF,
                                            const int*   __restrict__ EI,
                                            const float* __restrict__ DI,
                                            f16* __restrict__ w2c,
                                            f16* __restrict__ ht2,
                                            f16* __restrict__ tmo,
                                            float* __restrict__ out, int nz4) {
  __shared__ u32x4 smem_v[K_TOT / 16];
  char* smem = (char*)smem_v;
  const int bid = blockIdx.x, tid = threadIdx.x;

  if (bid < 516) {
    // ---- one K-step (32 j) of one W2ext row -> 2 frags per thread ----
    const int u = bid >> 2, s = bid & 3;
    const int i = tid >> 1, half = tid & 1;
    const float* src = ((u < 128) ? (W2 + (size_t)u * 16384) : b2)
                       + i * 128 + s * 32 + half * 16;
    union { f16 s16[16]; u32x4 v[2]; } pk;
#pragma unroll
    for (int q = 0; q < 4; ++q) {
      f32x4 v = *(const f32x4*)(src + q * 4);
#pragma unroll
      for (int r = 0; r < 4; ++r) pk.s16[q * 4 + r] = (f16)v[r];
    }
    const int nt = i >> 4, l15 = i & 15;
    u32x4* dst = (u32x4*)w2c + (size_t)(u * 4 + s) * 512 + nt * 64 + l15;
    dst[(half * 2 + 0) * 16] = pk.v[0];
    dst[(half * 2 + 1) * 16] = pk.v[1];
    return;
  }
  if (bid < 644) {
    const int bid2 = bid - 516;
    const int e0g = bid2 * 64;
    const int eb  = bid2 >> 1;
    const int el0 = (bid2 & 1) * 64;

    // ---- convert Wt -> LDS frags (2048 frags, 8 per thread) ----
#pragma unroll
    for (int q = 0; q < 8; ++q) {
      int f = q * 256 + tid;
      int lane = f & 63, nt = (f >> 6) & 7, step = f >> 9;
      int j = nt * 16 + (lane & 15);
      int u0 = step * 32 + (lane >> 4) * 8;
      union { f16 s[8]; u32x4 v; } pk;
#pragma unroll
      for (int r = 0; r < 8; ++r) pk.s[r] = (f16)WT[(u0 + r) * 128 + j];
      *(u32x4*)(smem + K_WTC + f * 16) = pk.v;
    }
    // ---- convert W1ext -> LDS frags (1024 frags, 4 per thread) ----
#pragma unroll
    for (int q = 0; q < 4; ++q) {
      int f = q * 256 + tid;
      int lane = f & 63, nt = (f >> 6) & 7, step = f >> 9;
      int j = nt * 16 + (lane & 15);
      union { f16 s[8]; u32x4 v; } pk;
#pragma unroll
      for (int r = 0; r < 8; ++r) {
        int g = step * 32 + (lane >> 4) * 8 + r;
        float v = (g < 50) ? W1[g * 128 + j] : ((g == 63) ? B1[j] : 0.0f);
        pk.s[r] = (f16)v;
      }
      *(u32x4*)(smem + K_W1C + f * 16) = pk.v;
    }
    // ---- mask ----
    if (tid < 64) {
      float d = DI[e0g + tid];
      *(float*)(smem + K_MSK + tid * 4) = (d <= 8.0f) ? 1.0f : 0.0f;
    }
    // ---- df = gauss(d) -> swizzled LDS (channel 63 = 1 for b1) ----
    {
      int e = tid >> 2, g0 = (tid & 3) * 16;
      float d = DI[e0g + e];
      union { f16 s[16]; u32x4 v[2]; } pk;
#pragma unroll
      for (int gg = 0; gg < 16; ++gg) {
        int g = g0 + gg;
        float x = d - (float)g * (30.0f / 49.0f);
        float v = (g < 50) ? __expf(-10.0f * x * x) : ((g == 63) ? 1.0f : 0.0f);
        pk.s[gg] = (f16)v;
      }
      int base = e * 128 + g0 * 2, sw = (e & 7) << 4;
      *(u32x4*)(smem + K_DF + ((base) ^ sw))      = pk.v[0];
      *(u32x4*)(smem + K_DF + ((base + 16) ^ sw)) = pk.v[1];
    }
    // ---- gather src rows -> f16 swizzled LDS ----
#pragma unroll
    for (int p = 0; p < 8; ++p) {
      int e = p * 8 + (tid >> 5);
      int u0 = (tid & 31) * 4;
      int row = EI[e0g + e];
      f32x4 v = *(const f32x4*)(NF + (size_t)row * 128 + u0);
      union { f16 s[4]; unsigned long long q; } pk;
#pragma unroll
      for (int r = 0; r < 4; ++r) pk.s[r] = (f16)v[r];
      int addr = e * 256 + u0 * 2;
      *(unsigned long long*)(smem + K_SRC + (addr ^ ((e & 7) << 4))) = pk.q;
    }
    __syncthreads();

    const int w = tid >> 6, lane = tid & 63;
    const int l15 = lane & 15, g4 = lane >> 4;
    const int erow = w * 16;
    const int asw = (l15 & 7) << 4;

    f32x4 at[8], ah[8];
#pragma unroll
    for (int nt = 0; nt < 8; ++nt) {
      at[nt] = (f32x4){0.f, 0.f, 0.f, 0.f};
      ah[nt] = (f32x4){0.f, 0.f, 0.f, 0.f};
    }
    // t = src @ Wt  (K = 128, 4 steps; B from LDS)
#pragma unroll
    for (int step = 0; step < 4; ++step) {
      int aaddr = (erow + l15) * 256 + step * 64 + g4 * 16;
      f16x8 a = *(const f16x8*)(smem + K_SRC + (aaddr ^ asw));
#pragma unroll
      for (int nt = 0; nt < 8; ++nt) {
        f16x8 b = *(const f16x8*)(smem + K_WTC + ((step * 8 + nt) * 64 + lane) * 16);
        at[nt] = __builtin_amdgcn_mfma_f32_16x16x32_f16(a, b, at[nt], 0, 0, 0);
      }
    }
    // h = df @ W1ext  (K = 64, 2 steps; B from LDS)
#pragma unroll
    for (int step = 0; step < 2; ++step) {
      int aaddr = (erow + l15) * 128 + step * 64 + g4 * 16;
      f16x8 a = *(const f16x8*)(smem + K_DF + (aaddr ^ asw));
#pragma unroll
      for (int nt = 0; nt < 8; ++nt) {
        f16x8 b = *(const f16x8*)(smem + K_W1C + ((step * 8 + nt) * 64 + lane) * 16);
        ah[nt] = __builtin_amdgcn_mfma_f32_16x16x32_f16(a, b, ah[nt], 0, 0, 0);
      }
    }
    // ---- epilogue t -> tmo (mask folded, pre-swizzled bytes) ----
    const float* mk = (const float*)(smem + K_MSK);
#pragma unroll
    for (int r = 0; r < 4; ++r) {
      int el_ = erow + g4 * 4 + r;
      float m = mk[el_];
      int sw2 = (el_ & 7) << 4;
      char* rowp = (char*)tmo + (size_t)(e0g + el_) * 256;
#pragma unroll
      for (int nt = 0; nt < 8; ++nt)
        *(f16*)(rowp + (((nt * 16 + l15) * 2) ^ sw2)) = (f16)(m * at[nt][r]);
    }
    // ---- epilogue h -> ht2 (silu, transposed store) ----
#pragma unroll
    for (int r = 0; r < 4; ++r) {
      int el_ = el0 + erow + g4 * 4 + r;
#pragma unroll
      for (int nt = 0; nt < 8; ++nt) {
        int u = nt * 16 + l15;
        ht2[((size_t)eb * 132 + u) * 128 + el_] = (f16)fsilu(ah[nt][r]);
      }
    }
    if (tid < 64) ht2[((size_t)eb * 132 + 128) * 128 + el0 + tid] = (f16)1.0f;
    return;
  }
  // ---- zero d_out ----
  {
    int base = (bid - 644) * 1024;
    f32x4 z = {0.f, 0.f, 0.f, 0.f};
#pragma unroll
    for (int k = 0; k < 4; ++k) {
      int i4 = base + k * 256 + tid;
      if (i4 < nz4) ((f32x4*)out)[i4] = z;
    }
  }
}

// ---------------- k2: fused outer-product GEMM + partial store --------------
// grid 512: chunk c = bid&7 (16 u, c==7: 17 incl. b2 row), eb = bid>>3.
// Block: 4 waves 2x2 over 128e x 128i; wave = 64e x 64i; acc[4][4] f32x4.
// MODE 0: plain f32 stores to fpart[e][c][i].  MODE 1: atomicAdd (fallback).
template<int MODE>
__global__ __launch_bounds__(256, 2) void k2_gemm(const f16* __restrict__ w2c,
                                                  const f16* __restrict__ ht2,
                                                  const f16* __restrict__ tm,
                                                  const int* __restrict__ EI,
                                                  float* __restrict__ fpart,
                                                  float* __restrict__ msg) {
  __shared__ u32x4 smem_v[LDS_TOT / 16];
  char* smem = (char*)smem_v;

  const int bid = blockIdx.x;
  const int c   = bid & 7;
  const int eb  = bid >> 3;
  const int e0  = eb * 128;
  const int nu  = (c == 7) ? 17 : 16;
  const int tid = threadIdx.x, w = tid >> 6, lane = tid & 63;
  const int l15 = lane & 15, g4 = lane >> 4;
  const int wm = w >> 1, wn = w & 1;

  // ---- B phases 0/1 issued FIRST: latency overlaps staging + barrier ----
  const char* bp = (const char*)w2c + (size_t)(c * 64) * 8192 + wn * 4096 + lane * 16;
  f16x8 B0[4], B1[4];
#pragma unroll
  for (int nt = 0; nt < 4; ++nt) B0[nt] = *(const f16x8*)(bp + nt * 1024);
#pragma unroll
  for (int nt = 0; nt < 4; ++nt) B1[nt] = *(const f16x8*)(bp + 8192 + nt * 1024);

  {
    const char* tsrc = (const char*)tm + (size_t)e0 * 256 + w * 8192;
#pragma unroll
    for (int q = 0; q < 8; ++q)
      gll16(tsrc + q * 1024 + lane * 16,
            smem + LDS_TM + w * 8192 + q * 1024 + lane * 16);
  }
  if (w == 0) {   // 20 h rows
    const char* hsrc = (const char*)ht2 + ((size_t)eb * 132 + c * 16) * 256;
#pragma unroll
    for (int q = 0; q < 5; ++q)
      gll16(hsrc + q * 1024 + lane * 16, smem + LDS_H + q * 1024 + lane * 16);
  }
  __syncthreads();

  f16x8 Tall[4][4];
  {
    const int tmrow = LDS_TM + (wm * 64 + l15) * 256;
    const int colsw = (l15 & 7) << 4;
#pragma unroll
    for (int rt = 0; rt < 4; ++rt)
#pragma unroll
      for (int jc = 0; jc < 4; ++jc)
        Tall[rt][jc] = *(const f16x8*)(smem + tmrow + rt * 4096 +
                                       ((jc * 64 + g4 * 16) ^ colsw));
  }
  const __half* hbase = (const __half*)(smem + LDS_H) + wm * 64 + l15;

  __half2 hc[4], hn[4];
#pragma unroll
  for (int rt = 0; rt < 4; ++rt) hc[rt] = __half2half2(hbase[rt * 16]);

  size_t off = 2 * 8192;
  f32x4 acc[4][4];
#pragma unroll
  for (int rt = 0; rt < 4; ++rt)
#pragma unroll
    for (int nt = 0; nt < 4; ++nt) acc[rt][nt] = (f32x4){0.f, 0.f, 0.f, 0.f};

  for (int u = 0; u < nu; ++u) {
#pragma unroll
    for (int jc = 0; jc < 4; ++jc) {
      if (jc == 1) {
#pragma unroll
        for (int rt = 0; rt < 4; ++rt)
          hn[rt] = __half2half2(hbase[(u + 1) * 128 + rt * 16]);
      }
      union uf { f16x8 v; __half2 h[4]; };
      uf a[4];
#pragma unroll
      for (int rt = 0; rt < 4; ++rt) {
        uf t; t.v = Tall[rt][jc];
#pragma unroll
        for (int q = 0; q < 4; ++q) a[rt].h[q] = __hmul2(t.h[q], hc[rt]);
      }
      __builtin_amdgcn_s_setprio(1);
#pragma unroll
      for (int nt = 0; nt < 4; ++nt) {
        if ((jc & 1) == 0) {
#pragma unroll
          for (int rt = 0; rt < 4; ++rt)
            acc[rt][nt] = __builtin_amdgcn_mfma_f32_16x16x32_f16(a[rt].v, B0[nt], acc[rt][nt], 0, 0, 0);
          B0[nt] = *(const f16x8*)(bp + off + nt * 1024);
        } else {
#pragma unroll
          for (int rt = 0; rt < 4; ++rt)
            acc[rt][nt] = __builtin_amdgcn_mfma_f32_16x16x32_f16(a[rt].v, B1[nt], acc[rt][nt], 0, 0, 0);
          B1[nt] = *(const f16x8*)(bp + off + nt * 1024);
        }
      }
      __builtin_amdgcn_s_setprio(0);
      off += 8192;
    }
#pragma unroll
    for (int rt = 0; rt < 4; ++rt) hc[rt] = hn[rt];
  }

  if (MODE == 0) {
#pragma unroll
    for (int rt = 0; rt < 4; ++rt) {
#pragma unroll
      for (int r = 0; r < 4; ++r) {
        int e = e0 + wm * 64 + rt * 16 + g4 * 4 + r;
        float* prow = fpart + ((size_t)e * 8 + c) * 128 + wn * 64 + l15;
#pragma unroll
        for (int nt = 0; nt < 4; ++nt)
          prow[nt * 16] = acc[rt][nt][r];
      }
    }
  } else {
    const int* dst = EI + NEDGE;
#pragma unroll
    for (int rt = 0; rt < 4; ++rt) {
#pragma unroll
      for (int r = 0; r < 4; ++r) {
        int e = e0 + wm * 64 + rt * 16 + g4 * 4 + r;
        float* row = msg + (size_t)dst[e] * 128 + wn * 64 + l15;
#pragma unroll
        for (int nt = 0; nt < 4; ++nt)
          atomicAdd(row + nt * 16, acc[rt][nt][r]);
      }
    }
  }
}

// -------- k4: sum 8 chunk-partials per edge (contiguous), scatter ----------
__global__ __launch_bounds__(256) void k4_reduce(const float* __restrict__ fp,
                                                 const int* __restrict__ EI,
                                                 float* __restrict__ out) {
  int gid = blockIdx.x * 256 + threadIdx.x;     // 262144 = 8192 e * 32
  int e  = gid >> 5;
  int i0 = (gid & 31) << 2;
  const float* ep = fp + (size_t)e * 1024 + i0; // [e][c][i], 8 c-rows x 512 B
  f32x4 s = {0.f, 0.f, 0.f, 0.f};
#pragma unroll
  for (int cc = 0; cc < 8; ++cc) {
    f32x4 v = *(const f32x4*)(ep + cc * 128);
    s[0] += v[0]; s[1] += v[1]; s[2] += v[2]; s[3] += v[3];
  }
  float* row = out + (size_t)EI[NEDGE + e] * 128 + i0;
  atomicAdd(row + 0, s[0]);
  atomicAdd(row + 1, s[1]);
  atomicAdd(row + 2, s[2]);
  atomicAdd(row + 3, s[3]);
}

// ---------------- k3: out = silu(out) ----------------------------------------
__global__ __launch_bounds__(256) void k3_silu(float* __restrict__ out, int n4) {
  int idx = blockIdx.x * 256 + threadIdx.x;
  int stride = gridDim.x * 256;
  f32x4* p = (f32x4*)out;
  for (; idx < n4; idx += stride) {
    f32x4 v = p[idx];
#pragma unroll
    for (int cc = 0; cc < 4; ++cc) v[cc] = fsilu(v[cc]);
    p[idx] = v;
  }
}

extern "C" void kernel_launch(void* const* d_in, const int* in_sizes, int n_in,
                              void* d_out, int out_size, void* d_ws, size_t ws_size,
                              hipStream_t stream) {
  const float* NF = (const float*)d_in[0];
  const int*   EI = (const int*)  d_in[1];
  const float* DI = (const float*)d_in[2];
  const float* W1 = (const float*)d_in[3];
  const float* B1 = (const float*)d_in[4];
  const float* W2 = (const float*)d_in[5];
  const float* B2 = (const float*)d_in[6];
  const float* WT = (const float*)d_in[7];
  float* out = (float*)d_out;

  char* base = (char*)d_ws;
  f16*   w2c = (f16*)base;
  f16*   ht2 = (f16*)(base + W2C_BYTES);
  f16*   tmo = (f16*)(base + W2C_BYTES + HT_BYTES);
  float* fp  = (float*)(base + W2C_BYTES + HT_BYTES + TM_BYTES);
  size_t need_min  = (size_t)W2C_BYTES + HT_BYTES + TM_BYTES;
  size_t need_fast = need_min + FP_BYTES;
  if (ws_size < need_min) return;  // insufficient scratch: fail loudly
  const bool fast = (ws_size >= need_fast);

  int nz4 = out_size / 4;
  int zb  = (nz4 + 1023) / 1024;
  kpre<<<dim3(644 + zb), dim3(256), 0, stream>>>(W2, B2, W1, B1, WT, NF, EI, DI,
                                                 w2c, ht2, tmo, out, nz4);
  if (fast) {
    k2_gemm<0><<<dim3(512),  dim3(256), 0, stream>>>(w2c, ht2, tmo, EI, fp, out);
    k4_reduce <<<dim3(1024), dim3(256), 0, stream>>>(fp, EI, out);
  } else {
    k2_gemm<1><<<dim3(512),  dim3(256), 0, stream>>>(w2c, ht2, tmo, EI, fp, out);
  }
  k3_silu<<<dim3(1024), dim3(256), 0, stream>>>(out, nz4);
}